// Round 1
// baseline (103.202 us; speedup 1.0000x reference)
//
#include <hip/hip_runtime.h>
#include <hip/hip_bf16.h>

#define VOCAB 50257
#define NTAGS 50
#define EMB   128
#define NTOK  262144
#define KD    640     // (2*CTX+1) * EMB
#define WPAD  64      // tags padded to 4 MFMA n-tiles

typedef __attribute__((ext_vector_type(4))) float f32x4;
typedef __attribute__((ext_vector_type(8))) short bf16x8;

__device__ __forceinline__ ushort f2bf(float f) {
    union { float f; unsigned u; } v; v.f = f;
    unsigned u = v.u;
    return (ushort)((u + 0x7fffu + ((u >> 16) & 1u)) >> 16);  // RNE
}

// emb_table fp32 -> bf16, plus one zero row at index VOCAB (window padding)
__global__ void conv_emb_k(const float* __restrict__ src, ushort* __restrict__ dst) {
    int i = blockIdx.x * blockDim.x + threadIdx.x;
    int idx = i * 4;
    const int total = (VOCAB + 1) * EMB;
    if (idx >= total) return;
    float4 v = {0.f, 0.f, 0.f, 0.f};
    if (idx < VOCAB * EMB) v = *(const float4*)(src + idx);
    ushort4 o = { f2bf(v.x), f2bf(v.y), f2bf(v.z), f2bf(v.w) };
    *(ushort4*)(dst + idx) = o;
}

// W fp32 [50][640] -> bf16 [64][640], pad rows zeroed
__global__ void conv_w_k(const float* __restrict__ W, ushort* __restrict__ dst) {
    int i = blockIdx.x * blockDim.x + threadIdx.x;
    if (i >= WPAD * KD) return;
    int tag = i / KD;
    dst[i] = f2bf(tag < NTAGS ? W[i] : 0.f);
}

__global__ __launch_bounds__(256)
void tagger_k(const int* __restrict__ tokens, const ushort* __restrict__ embb,
              const ushort* __restrict__ Wb, const float* __restrict__ bias,
              float* __restrict__ out) {
    const int lane = threadIdx.x & 63;
    const int wave = threadIdx.x >> 6;
    const int c = lane & 15;   // A row / B col / D col selector
    const int q = lane >> 4;   // k-chunk / D row-group selector
    const int base = blockIdx.x * 256 + wave * 64;   // first token of this wave

    f32x4 acc[4][4];
    #pragma unroll
    for (int mt = 0; mt < 4; ++mt)
        #pragma unroll
        for (int nt = 0; nt < 4; ++nt)
            acc[mt][nt] = (f32x4){0.f, 0.f, 0.f, 0.f};

    const int ZROW = VOCAB * EMB;   // zero row offset (bf16 elements)

    #pragma unroll
    for (int p = 0; p < 5; ++p) {
        int eoff[4];
        #pragma unroll
        for (int mt = 0; mt < 4; ++mt) {
            int t = base + mt * 16 + c + p - 2;      // token index for this A row
            eoff[mt] = (t >= 0 && t < NTOK) ? tokens[t] * EMB : ZROW;
        }
        #pragma unroll
        for (int kk = 0; kk < 4; ++kk) {
            const int kf = p * 128 + kk * 32 + q * 8;
            bf16x8 a[4], bb[4];
            #pragma unroll
            for (int mt = 0; mt < 4; ++mt)
                a[mt] = *(const bf16x8*)(embb + eoff[mt] + kk * 32 + q * 8);
            #pragma unroll
            for (int nt = 0; nt < 4; ++nt)
                bb[nt] = *(const bf16x8*)(Wb + (nt * 16 + c) * KD + kf);
            #pragma unroll
            for (int mt = 0; mt < 4; ++mt)
                #pragma unroll
                for (int nt = 0; nt < 4; ++nt)
                    acc[mt][nt] = __builtin_amdgcn_mfma_f32_16x16x32_bf16(
                        a[mt], bb[nt], acc[mt][nt], 0, 0, 0);
        }
    }

    float bv[4];
    #pragma unroll
    for (int nt = 0; nt < 4; ++nt) {
        int tag = nt * 16 + c;
        bv[nt] = (tag < NTAGS) ? bias[tag] : 0.f;
    }

    #pragma unroll
    for (int mt = 0; mt < 4; ++mt) {
        #pragma unroll
        for (int j = 0; j < 4; ++j) {
            const int row = base + mt * 16 + q * 4 + j;
            float v[4];
            float m = -1e30f;
            #pragma unroll
            for (int nt = 0; nt < 4; ++nt) {
                float x = acc[mt][nt][j] + bv[nt];
                v[nt] = x;
                if (nt * 16 + c < NTAGS) m = fmaxf(m, x);
            }
            #pragma unroll
            for (int mask = 8; mask >= 1; mask >>= 1)
                m = fmaxf(m, __shfl_xor(m, mask));
            float s = 0.f;
            #pragma unroll
            for (int nt = 0; nt < 4; ++nt)
                if (nt * 16 + c < NTAGS) s += __expf(v[nt] - m);
            #pragma unroll
            for (int mask = 8; mask >= 1; mask >>= 1)
                s += __shfl_xor(s, mask);
            const float L = m + __logf(s);
            #pragma unroll
            for (int nt = 0; nt < 4; ++nt) {
                int tag = nt * 16 + c;
                if (tag < NTAGS) out[row * NTAGS + tag] = v[nt] - L;
            }
        }
    }
}

extern "C" void kernel_launch(void* const* d_in, const int* in_sizes, int n_in,
                              void* d_out, int out_size, void* d_ws, size_t ws_size,
                              hipStream_t stream) {
    const int*   tokens = (const int*)d_in[0];
    const float* emb    = (const float*)d_in[1];
    const float* W      = (const float*)d_in[2];
    const float* b      = (const float*)d_in[3];
    float* out = (float*)d_out;

    ushort* embb = (ushort*)d_ws;                               // (VOCAB+1)*128 bf16
    ushort* Wb   = embb + (size_t)(VOCAB + 1) * EMB;            // 64*640 bf16

    {
        int nthreads = (VOCAB + 1) * EMB / 4;
        conv_emb_k<<<(nthreads + 255) / 256, 256, 0, stream>>>(emb, embb);
    }
    {
        int nthreads = WPAD * KD;
        conv_w_k<<<(nthreads + 255) / 256, 256, 0, stream>>>(W, Wb);
    }
    tagger_k<<<NTOK / 256, 256, 0, stream>>>(tokens, embb, Wb, b, out);
}

// Round 2
// 85.731 us; speedup vs baseline: 1.2038x; 1.2038x over previous
//
#include <hip/hip_runtime.h>
#include <hip/hip_bf16.h>

#define VOCAB 50257
#define NTAGS 50
#define EMB   128
#define NTOK  262144
#define KD    640     // (2*CTX+1) * EMB
#define WPAD  64      // tags padded to 4 MFMA n-tiles

#define TPB   192     // 3 waves
#define TOKPB 192     // tokens per block
#define ROWS  204     // 51 groups of 4 staged rows (192 + 4 boundary + pad)

typedef __attribute__((ext_vector_type(4))) float f32x4;
typedef __attribute__((ext_vector_type(8))) short bf16x8;

__device__ __forceinline__ ushort f2bf(float f) {
    union { float f; unsigned u; } v; v.f = f;
    unsigned u = v.u;
    return (ushort)((u + 0x7fffu + ((u >> 16) & 1u)) >> 16);  // RNE
}

__device__ __forceinline__ void gload_lds16(const void* g, void* l) {
    __builtin_amdgcn_global_load_lds(
        (const __attribute__((address_space(1))) unsigned*)g,
        (__attribute__((address_space(3))) unsigned*)l, 16, 0, 0);
}

// fused: emb_table fp32 -> bf16 (+1 zero row at VOCAB), W fp32 [50][640] -> bf16 [64][640]
__global__ void conv_k(const float* __restrict__ emb, const float* __restrict__ W,
                       ushort* __restrict__ embb, ushort* __restrict__ wb) {
    const int etotal = (VOCAB + 1) * EMB;
    int idx = (blockIdx.x * blockDim.x + threadIdx.x) * 4;
    if (idx < etotal) {
        float4 v = {0.f, 0.f, 0.f, 0.f};
        if (idx < VOCAB * EMB) v = *(const float4*)(emb + idx);
        ushort4 o = { f2bf(v.x), f2bf(v.y), f2bf(v.z), f2bf(v.w) };
        *(ushort4*)(embb + idx) = o;
    } else {
        int wi = idx - etotal;
        if (wi < WPAD * KD) {
            #pragma unroll
            for (int k = 0; k < 4; ++k) {
                int j = wi + k;
                int tag = j / KD;
                wb[j] = f2bf(tag < NTAGS ? W[j] : 0.f);
            }
        }
    }
}

__global__ __launch_bounds__(TPB)
void tagger_k(const int* __restrict__ tokens, const ushort* __restrict__ embb,
              const ushort* __restrict__ Wb, const float* __restrict__ bias,
              float* __restrict__ out) {
    __shared__ ushort smem[ROWS * EMB];   // 204 rows x 256 B = 52.2 KB, chunk-swizzled

    const int tid  = threadIdx.x;
    const int lane = tid & 63;
    const int wave = tid >> 6;
    const int c = lane & 15;   // A row (token) / B row (tag) / D col selector
    const int q = lane >> 4;   // k-chunk / D row-group selector
    const int bb = blockIdx.x * TOKPB;

    // ---- phase 1: stage rows [bb-2, bb+201] into LDS ----
    // LDS row i holds emb row of token (bb-2+i), 16 chunks of 16 B,
    // logical chunk j stored at physical chunk j ^ (i&7)  (T2 swizzle via
    // pre-swizzled GLOBAL source, LDS dest linear -> global_load_lds legal).
    {
        const int rsub = lane >> 4;     // row within 4-row group
        const int pc   = lane & 15;     // physical chunk this lane fills
        #pragma unroll
        for (int it = 0; it < 17; ++it) {
            int g = wave * 17 + it;     // group index, wave-uniform
            int i = g * 4 + rsub;       // LDS row
            int t = bb - 2 + i;
            int tok = (t >= 0 && t < NTOK) ? tokens[t] : VOCAB;  // VOCAB = zero row
            int sc = pc ^ (i & 7);      // source (logical) chunk
            const ushort* src = embb + (size_t)tok * EMB + sc * 8;
            gload_lds16(src, (char*)smem + g * 1024);
        }
    }
    __syncthreads();

    // ---- phase 2: 64 tokens x 64 tags MFMA per wave, A from LDS ----
    f32x4 acc[4][4];
    #pragma unroll
    for (int mt = 0; mt < 4; ++mt)
        #pragma unroll
        for (int nt = 0; nt < 4; ++nt)
            acc[mt][nt] = (f32x4){0.f, 0.f, 0.f, 0.f};

    const int wbase = wave * 64;

    #pragma unroll
    for (int p = 0; p < 5; ++p) {
        #pragma unroll
        for (int kk = 0; kk < 4; ++kk) {
            bf16x8 a[4], bf[4];
            #pragma unroll
            for (int mt = 0; mt < 4; ++mt) {
                int r  = wbase + mt * 16 + c + p;          // LDS row
                int pc = (4 * kk + q) ^ (r & 7);           // physical chunk
                a[mt] = *(const bf16x8*)((const char*)smem + r * 256 + pc * 16);
            }
            const int kf = p * 128 + kk * 32 + q * 8;
            #pragma unroll
            for (int nt = 0; nt < 4; ++nt)
                bf[nt] = *(const bf16x8*)(Wb + (nt * 16 + c) * KD + kf);
            #pragma unroll
            for (int mt = 0; mt < 4; ++mt)
                #pragma unroll
                for (int nt = 0; nt < 4; ++nt)
                    acc[mt][nt] = __builtin_amdgcn_mfma_f32_16x16x32_bf16(
                        a[mt], bf[nt], acc[mt][nt], 0, 0, 0);
        }
    }

    // ---- epilogue: bias + log-softmax over 50 tags (16-lane shfl groups) ----
    float bv[4];
    #pragma unroll
    for (int nt = 0; nt < 4; ++nt) {
        int tag = nt * 16 + c;
        bv[nt] = (tag < NTAGS) ? bias[tag] : 0.f;
    }

    #pragma unroll
    for (int mt = 0; mt < 4; ++mt) {
        #pragma unroll
        for (int j = 0; j < 4; ++j) {
            const int row = bb + wave * 64 + mt * 16 + q * 4 + j;
            float v[4];
            float m = -1e30f;
            #pragma unroll
            for (int nt = 0; nt < 4; ++nt) {
                float x = acc[mt][nt][j] + bv[nt];
                v[nt] = x;
                if (nt * 16 + c < NTAGS) m = fmaxf(m, x);
            }
            #pragma unroll
            for (int mask = 8; mask >= 1; mask >>= 1)
                m = fmaxf(m, __shfl_xor(m, mask));
            float s = 0.f;
            #pragma unroll
            for (int nt = 0; nt < 4; ++nt)
                if (nt * 16 + c < NTAGS) s += __expf(v[nt] - m);
            #pragma unroll
            for (int mask = 8; mask >= 1; mask >>= 1)
                s += __shfl_xor(s, mask);
            const float L = m + __logf(s);
            if (row < NTOK) {
                #pragma unroll
                for (int nt = 0; nt < 4; ++nt) {
                    int tag = nt * 16 + c;
                    if (tag < NTAGS) out[row * NTAGS + tag] = v[nt] - L;
                }
            }
        }
    }
}

extern "C" void kernel_launch(void* const* d_in, const int* in_sizes, int n_in,
                              void* d_out, int out_size, void* d_ws, size_t ws_size,
                              hipStream_t stream) {
    const int*   tokens = (const int*)d_in[0];
    const float* emb    = (const float*)d_in[1];
    const float* W      = (const float*)d_in[2];
    const float* b      = (const float*)d_in[3];
    float* out = (float*)d_out;

    ushort* embb = (ushort*)d_ws;                               // (VOCAB+1)*128 bf16
    ushort* Wb   = embb + (size_t)(VOCAB + 1) * EMB;            // 64*640 bf16

    {
        const int etotal = (VOCAB + 1) * EMB;
        const int total4 = (etotal + WPAD * KD) / 4;
        conv_k<<<(total4 + 255) / 256, 256, 0, stream>>>(emb, W, embb, Wb);
    }
    {
        const int nblk = (NTOK + TOKPB - 1) / TOKPB;            // 1366
        tagger_k<<<nblk, TPB, 0, stream>>>(tokens, embb, Wb, b, out);
    }
}

// Round 3
// 81.857 us; speedup vs baseline: 1.2608x; 1.0473x over previous
//
#include <hip/hip_runtime.h>
#include <hip/hip_bf16.h>

#define VOCAB 50257
#define NTAGS 50
#define EMB   128
#define NTOK  262144
#define KD    640     // (2*CTX+1) * EMB
#define WPAD  64      // tags padded to 4 MFMA n-tiles

#define TPB   64      // 1 wave per block -> no barrier convoy, 9 blocks/CU
#define TOKPB 64      // tokens per block
#define ROWS  68      // 17 groups of 4 staged rows (64 + 4 halo)

typedef __attribute__((ext_vector_type(4))) float f32x4;
typedef __attribute__((ext_vector_type(8))) short bf16x8;

__device__ __forceinline__ ushort f2bf(float f) {
    union { float f; unsigned u; } v; v.f = f;
    unsigned u = v.u;
    return (ushort)((u + 0x7fffu + ((u >> 16) & 1u)) >> 16);  // RNE
}

__device__ __forceinline__ void gload_lds16(const void* g, void* l) {
    __builtin_amdgcn_global_load_lds(
        (const __attribute__((address_space(1))) unsigned*)g,
        (__attribute__((address_space(3))) unsigned*)l, 16, 0, 0);
}

// fused: emb_table fp32 -> bf16 (+1 zero row at VOCAB), W fp32 [50][640] -> bf16 [64][640]
__global__ void conv_k(const float* __restrict__ emb, const float* __restrict__ W,
                       ushort* __restrict__ embb, ushort* __restrict__ wb) {
    const int etotal = (VOCAB + 1) * EMB;
    int idx = (blockIdx.x * blockDim.x + threadIdx.x) * 4;
    if (idx < etotal) {
        float4 v = {0.f, 0.f, 0.f, 0.f};
        if (idx < VOCAB * EMB) v = *(const float4*)(emb + idx);
        ushort4 o = { f2bf(v.x), f2bf(v.y), f2bf(v.z), f2bf(v.w) };
        *(ushort4*)(embb + idx) = o;
    } else {
        int wi = idx - etotal;
        if (wi < WPAD * KD) {
            #pragma unroll
            for (int k = 0; k < 4; ++k) {
                int j = wi + k;
                int tag = j / KD;
                wb[j] = f2bf(tag < NTAGS ? W[j] : 0.f);
            }
        }
    }
}

__global__ __launch_bounds__(TPB)
void tagger_k(const int* __restrict__ tokens, const ushort* __restrict__ embb,
              const ushort* __restrict__ Wb, const float* __restrict__ bias,
              float* __restrict__ out) {
    __shared__ ushort smem[ROWS * EMB];   // 68 rows x 256 B = 17 KB, chunk-swizzled

    const int lane = threadIdx.x & 63;
    const int c = lane & 15;   // A row (token) / B row (tag) / D col selector
    const int q = lane >> 4;   // k-chunk / D row-group selector
    const int bb = blockIdx.x * TOKPB;

    // ---- phase 1: stage rows [bb-2, bb+65] into LDS ----
    // LDS row i holds emb row of token (bb-2+i), 16 chunks of 16 B,
    // logical chunk j stored at physical chunk j ^ (i&7)  (swizzle via
    // pre-swizzled GLOBAL source; LDS dest linear -> global_load_lds legal).
    {
        const int rsub = lane >> 4;     // row within 4-row group
        const int pc   = lane & 15;     // physical chunk this lane fills
        #pragma unroll
        for (int g = 0; g < 17; ++g) {
            int i = g * 4 + rsub;       // LDS row
            int t = bb - 2 + i;
            int tok = (t >= 0 && t < NTOK) ? tokens[t] : VOCAB;  // VOCAB = zero row
            int sc = pc ^ (i & 7);      // source (logical) chunk
            gload_lds16(embb + (size_t)tok * EMB + sc * 8, (char*)smem + g * 1024);
        }
    }
    __syncthreads();   // 1-wave block: this is just the vmcnt/lgkm drain

    // ---- phase 2: 64 tokens x 64 tags MFMA, A from LDS, B from L2 ----
    f32x4 acc[4][4];
    #pragma unroll
    for (int mt = 0; mt < 4; ++mt)
        #pragma unroll
        for (int nt = 0; nt < 4; ++nt)
            acc[mt][nt] = (f32x4){0.f, 0.f, 0.f, 0.f};

    #pragma unroll
    for (int p = 0; p < 5; ++p) {
        #pragma unroll
        for (int kk = 0; kk < 4; ++kk) {
            bf16x8 a[4], bf[4];
            #pragma unroll
            for (int mt = 0; mt < 4; ++mt) {
                int r  = mt * 16 + c + p;                  // LDS row
                int pc = (4 * kk + q) ^ (r & 7);           // physical chunk
                a[mt] = *(const bf16x8*)((const char*)smem + r * 256 + pc * 16);
            }
            const int kf = p * 128 + kk * 32 + q * 8;
            #pragma unroll
            for (int nt = 0; nt < 4; ++nt)
                bf[nt] = *(const bf16x8*)(Wb + (nt * 16 + c) * KD + kf);
            __builtin_amdgcn_s_setprio(1);
            #pragma unroll
            for (int mt = 0; mt < 4; ++mt)
                #pragma unroll
                for (int nt = 0; nt < 4; ++nt)
                    acc[mt][nt] = __builtin_amdgcn_mfma_f32_16x16x32_bf16(
                        a[mt], bf[nt], acc[mt][nt], 0, 0, 0);
            __builtin_amdgcn_s_setprio(0);
        }
    }

    // ---- epilogue: bias + log-softmax over 50 tags (16-lane shfl groups) ----
    float bv[4];
    #pragma unroll
    for (int nt = 0; nt < 4; ++nt) {
        int tag = nt * 16 + c;
        bv[nt] = (tag < NTAGS) ? bias[tag] : 0.f;
    }

    #pragma unroll
    for (int mt = 0; mt < 4; ++mt) {
        #pragma unroll
        for (int j = 0; j < 4; ++j) {
            const int row = bb + mt * 16 + q * 4 + j;
            float v[4];
            float m = -1e30f;
            #pragma unroll
            for (int nt = 0; nt < 4; ++nt) {
                float x = acc[mt][nt][j] + bv[nt];
                v[nt] = x;
                if (nt * 16 + c < NTAGS) m = fmaxf(m, x);
            }
            #pragma unroll
            for (int mask = 8; mask >= 1; mask >>= 1)
                m = fmaxf(m, __shfl_xor(m, mask));
            float s = 0.f;
            #pragma unroll
            for (int nt = 0; nt < 4; ++nt)
                if (nt * 16 + c < NTAGS) s += __expf(v[nt] - m);
            #pragma unroll
            for (int mask = 8; mask >= 1; mask >>= 1)
                s += __shfl_xor(s, mask);
            const float L = m + __logf(s);
            #pragma unroll
            for (int nt = 0; nt < 4; ++nt) {
                int tag = nt * 16 + c;
                if (tag < NTAGS) out[row * NTAGS + tag] = v[nt] - L;
            }
        }
    }
}

extern "C" void kernel_launch(void* const* d_in, const int* in_sizes, int n_in,
                              void* d_out, int out_size, void* d_ws, size_t ws_size,
                              hipStream_t stream) {
    const int*   tokens = (const int*)d_in[0];
    const float* emb    = (const float*)d_in[1];
    const float* W      = (const float*)d_in[2];
    const float* b      = (const float*)d_in[3];
    float* out = (float*)d_out;

    ushort* embb = (ushort*)d_ws;                               // (VOCAB+1)*128 bf16
    ushort* Wb   = embb + (size_t)(VOCAB + 1) * EMB;            // 64*640 bf16

    {
        const int etotal = (VOCAB + 1) * EMB;
        const int total4 = (etotal + WPAD * KD) / 4;
        conv_k<<<(total4 + 255) / 256, 256, 0, stream>>>(emb, W, embb, Wb);
    }
    {
        const int nblk = NTOK / TOKPB;                          // 4096
        tagger_k<<<nblk, TPB, 0, stream>>>(tokens, embb, Wb, b, out);
    }
}

// Round 4
// 74.192 us; speedup vs baseline: 1.3910x; 1.1033x over previous
//
#include <hip/hip_runtime.h>
#include <hip/hip_bf16.h>

#define VOCAB 50257
#define NTAGS 50
#define EMB   128
#define NTOK  262144
#define KD    640     // (2*CTX+1) * EMB
#define WPAD  64      // tags padded to 4 MFMA n-tiles

#define TPB   64      // 1 wave per block
#define TOKPB 64      // tokens per block
#define ROWS  68      // 64 + 4 halo staged rows
#define STEPS 20      // 5 positions x 4 k-chunks

typedef __attribute__((ext_vector_type(4))) float f32x4;
typedef __attribute__((ext_vector_type(8))) short bf16x8;

__device__ __forceinline__ ushort f2bf(float f) {
    union { float f; unsigned u; } v; v.f = f;
    unsigned u = v.u;
    return (ushort)((u + 0x7fffu + ((u >> 16) & 1u)) >> 16);  // RNE
}

__device__ __forceinline__ void gload_lds16(const void* g, void* l) {
    __builtin_amdgcn_global_load_lds(
        (const __attribute__((address_space(1))) unsigned*)g,
        (__attribute__((address_space(3))) unsigned*)l, 16, 0, 0);
}

// fused: emb_table fp32 -> bf16 (+1 zero row at VOCAB), W fp32 [50][640] -> bf16 [64][640]
__global__ void conv_k(const float* __restrict__ emb, const float* __restrict__ W,
                       ushort* __restrict__ embb, ushort* __restrict__ wb) {
    const int etotal = (VOCAB + 1) * EMB;
    int idx = (blockIdx.x * blockDim.x + threadIdx.x) * 4;
    if (idx < etotal) {
        float4 v = {0.f, 0.f, 0.f, 0.f};
        if (idx < VOCAB * EMB) v = *(const float4*)(emb + idx);
        ushort4 o = { f2bf(v.x), f2bf(v.y), f2bf(v.z), f2bf(v.w) };
        *(ushort4*)(embb + idx) = o;
    } else {
        int wi = idx - etotal;
        if (wi < WPAD * KD) {
            #pragma unroll
            for (int k = 0; k < 4; ++k) {
                int j = wi + k;
                int tag = j / KD;
                wb[j] = f2bf(tag < NTAGS ? W[j] : 0.f);
            }
        }
    }
}

__global__ __launch_bounds__(TPB, 2)   // allow up to 256 VGPR for deep load pipelining
void tagger_k(const int* __restrict__ tokens, const ushort* __restrict__ embb,
              const ushort* __restrict__ Wb, const float* __restrict__ bias,
              float* __restrict__ out) {
    __shared__ ushort smem[ROWS * EMB];   // 68 rows x 256 B = 17 KB, chunk-swizzled

    const int lane = threadIdx.x & 63;
    const int c = lane & 15;   // A row (token) / B row (tag) / D col selector
    const int q = lane >> 4;   // k-chunk / D row-group selector
    const int bb = blockIdx.x * TOKPB;
    const int rsub = lane >> 4;

    // ---- token ids for the 17 staging groups (batched, independent loads) ----
    int tokid[17];
    #pragma unroll
    for (int g = 0; g < 17; ++g) {
        int t = bb - 2 + g * 4 + rsub;
        tokid[g] = (t >= 0 && t < NTOK) ? tokens[t] : VOCAB;   // VOCAB = zero row
    }

    // ---- B fragment bases: lane-dependent part once, rest is immediates ----
    const ushort* bp[4];
    #pragma unroll
    for (int nt = 0; nt < 4; ++nt)
        bp[nt] = Wb + (nt * 16 + c) * KD + q * 8;

    // ---- prefetch B for pipeline steps 0..3 (independent of LDS staging) ----
    bf16x8 Bb[4][4];
    #pragma unroll
    for (int s = 0; s < 4; ++s)
        #pragma unroll
        for (int nt = 0; nt < 4; ++nt)
            Bb[s][nt] = *(const bf16x8*)(bp[nt] + (s >> 2) * 128 + (s & 3) * 32);

    // ---- bias early (clamped index; tags >= NTAGS masked in epilogue) ----
    float bv[4];
    #pragma unroll
    for (int nt = 0; nt < 4; ++nt) {
        int tag = nt * 16 + c;
        bv[nt] = bias[tag < NTAGS ? tag : NTAGS - 1];
    }

    // ---- stage rows [bb-2, bb+65] into LDS ----
    // LDS row i = emb row of token (bb-2+i); logical chunk j at physical j^(i&7)
    // (swizzle via pre-swizzled GLOBAL source; LDS dest linear).
    {
        const int pc = lane & 15;
        #pragma unroll
        for (int g = 0; g < 17; ++g) {
            int i = g * 4 + rsub;
            int sc = pc ^ (i & 7);
            gload_lds16(embb + (size_t)tokid[g] * EMB + sc * 8, (char*)smem + g * 1024);
        }
    }
    __syncthreads();   // 1-wave block: effectively the vmcnt drain

    f32x4 acc[4][4];
    #pragma unroll
    for (int mt = 0; mt < 4; ++mt)
        #pragma unroll
        for (int nt = 0; nt < 4; ++nt)
            acc[mt][nt] = (f32x4){0.f, 0.f, 0.f, 0.f};

    // ---- A prefetch steps 0,1 ----
    bf16x8 Ab[2][4];
    #pragma unroll
    for (int s = 0; s < 2; ++s) {
        int p = s >> 2, kk = s & 3;
        int h = (c + p) & 7;
        int ch = (4 * kk + q) ^ h;
        const char* ab = (const char*)smem + (c + p) * 256 + ch * 16;
        #pragma unroll
        for (int mt = 0; mt < 4; ++mt)
            Ab[s][mt] = *(const bf16x8*)(ab + mt * 4096);
    }

    // ---- pipelined k-loop: MFMA(s) | issue B(s+4) | issue A(s+2) ----
    #pragma unroll
    for (int s = 0; s < STEPS; ++s) {
        __builtin_amdgcn_s_setprio(1);
        #pragma unroll
        for (int mt = 0; mt < 4; ++mt)
            #pragma unroll
            for (int nt = 0; nt < 4; ++nt)
                acc[mt][nt] = __builtin_amdgcn_mfma_f32_16x16x32_bf16(
                    Ab[s & 1][mt], Bb[s & 3][nt], acc[mt][nt], 0, 0, 0);
        __builtin_amdgcn_s_setprio(0);
        if (s + 4 < STEPS) {
            const int t = s + 4, p = t >> 2, kk = t & 3;
            #pragma unroll
            for (int nt = 0; nt < 4; ++nt)
                Bb[s & 3][nt] = *(const bf16x8*)(bp[nt] + p * 128 + kk * 32);
        }
        if (s + 2 < STEPS) {
            const int t = s + 2, p = t >> 2, kk = t & 3;
            int h = (c + p) & 7;
            int ch = (4 * kk + q) ^ h;
            const char* ab = (const char*)smem + (c + p) * 256 + ch * 16;
            #pragma unroll
            for (int mt = 0; mt < 4; ++mt)
                Ab[s & 1][mt] = *(const bf16x8*)(ab + mt * 4096);
        }
    }

    // ---- epilogue: bias + log-softmax over 50 tags (16-lane shfl groups) ----
    #pragma unroll
    for (int mt = 0; mt < 4; ++mt) {
        #pragma unroll
        for (int j = 0; j < 4; ++j) {
            const int row = bb + mt * 16 + q * 4 + j;
            float v[4];
            float m = -1e30f;
            #pragma unroll
            for (int nt = 0; nt < 4; ++nt) {
                float x = acc[mt][nt][j] + bv[nt];
                v[nt] = x;
                if (nt * 16 + c < NTAGS) m = fmaxf(m, x);
            }
            #pragma unroll
            for (int mask = 8; mask >= 1; mask >>= 1)
                m = fmaxf(m, __shfl_xor(m, mask));
            float s = 0.f;
            #pragma unroll
            for (int nt = 0; nt < 4; ++nt)
                if (nt * 16 + c < NTAGS) s += __expf(v[nt] - m);
            #pragma unroll
            for (int mask = 8; mask >= 1; mask >>= 1)
                s += __shfl_xor(s, mask);
            const float L = m + __logf(s);
            #pragma unroll
            for (int nt = 0; nt < 4; ++nt) {
                int tag = nt * 16 + c;
                if (tag < NTAGS) out[row * NTAGS + tag] = v[nt] - L;
            }
        }
    }
}

extern "C" void kernel_launch(void* const* d_in, const int* in_sizes, int n_in,
                              void* d_out, int out_size, void* d_ws, size_t ws_size,
                              hipStream_t stream) {
    const int*   tokens = (const int*)d_in[0];
    const float* emb    = (const float*)d_in[1];
    const float* W      = (const float*)d_in[2];
    const float* b      = (const float*)d_in[3];
    float* out = (float*)d_out;

    ushort* embb = (ushort*)d_ws;                               // (VOCAB+1)*128 bf16
    ushort* Wb   = embb + (size_t)(VOCAB + 1) * EMB;            // 64*640 bf16

    {
        const int etotal = (VOCAB + 1) * EMB;
        const int total4 = (etotal + WPAD * KD) / 4;
        conv_k<<<(total4 + 255) / 256, 256, 0, stream>>>(emb, W, embb, Wb);
    }
    {
        const int nblk = NTOK / TOKPB;                          // 4096
        tagger_k<<<nblk, TPB, 0, stream>>>(tokens, embb, Wb, b, out);
    }
}